// Round 10
// baseline (270.388 us; speedup 1.0000x reference)
//
#include <hip/hip_runtime.h>
#include <math.h>

#define NN   32768
#define EE   524288
#define ETOT (EE + NN)
#define BB   32
#define NPG  1024
#define RPG  17408          // CSR entries per graph = 16384 + 1024 self-loops
#define KK   512
#define INC  128
#define HID  64
#define NH   4
#define CC   256
#define SLOPE 0.2f

typedef __attribute__((ext_vector_type(8))) short short8;   // 8 bf16 = 4 VGPRs
typedef __attribute__((ext_vector_type(4))) float f32x4;

static __device__ inline unsigned short f2bf(float f) {      // fp32 -> bf16 RNE
  unsigned u = __float_as_uint(f);
  unsigned r = (u + 0x7FFFu + ((u >> 16) & 1u)) >> 16;
  return (unsigned short)r;
}

// ---------------- prep (parallel): consts + Mg + bf16 transposes ----------------
__global__ __launch_bounds__(256) void prep_kernel(const float* __restrict__ W,
                                                   const float* __restrict__ a_src,
                                                   const float* __restrict__ a_dst,
                                                   const float* __restrict__ b_gat,
                                                   const float* __restrict__ W_lin,
                                                   const float* __restrict__ b_lin,
                                                   const float* __restrict__ p,
                                                   float* __restrict__ Mg,
                                                   float* __restrict__ cbuf,
                                                   unsigned short* __restrict__ Wt,
                                                   unsigned short* __restrict__ Wlt) {
  const int b = blockIdx.x, t = threadIdx.x;
  if (b >= 17) {                                    // transposes
    int idx = (b - 17) * 256 + t;
    if (idx < 32768) {                              // Wt[c][k] = W[k][c]
      int c = idx >> 7, k = idx & 127;
      Wt[idx] = f2bf(W[k * 256 + c]);
    } else {                                        // Wlt[c][k] = W_lin[k][c]
      int i2 = idx - 32768;
      int c = i2 >> 8, k = i2 & 255;
      Wlt[i2] = f2bf(W_lin[k * 64 + c]);
    }
    return;
  }
  __shared__ float pl[64];
  __shared__ float ql[256];
  __shared__ float red[256];
  __shared__ float red2[256];
  if (t < 64) pl[t] = p[t];
  __syncthreads();
  {                                                 // q[t] = dot(W_lin[t], p)
    float acc = 0.f;
    const float* wr = W_lin + t * 64;
#pragma unroll
    for (int c = 0; c < 64; c += 4) {
      float4 wv = *(const float4*)(wr + c);
      acc += wv.x * pl[c] + wv.y * pl[c + 1] + wv.z * pl[c + 2] + wv.w * pl[c + 3];
    }
    ql[t] = acc;
  }
  __syncthreads();
  if (b == 0) {                                     // cq + rnorm via LDS trees
    float r = ql[t] * b_gat[t];
    if (t < 64) r += b_lin[t] * pl[t];
    red[t] = r;
    red2[t] = (t < 64) ? pl[t] * pl[t] : 0.f;
    __syncthreads();
    for (int s2 = 128; s2 > 0; s2 >>= 1) {
      if (t < s2) { red[t] += red[t + s2]; red2[t] += red2[t + s2]; }
      __syncthreads();
    }
    if (t == 0) { cbuf[0] = red[0]; cbuf[1] = 1.0f / sqrtf(red2[0]); }
    return;
  }
  if (t < 96) {                                     // blocks 1..16: 8 rows x 12 cols
    const int i = (b - 1) * 8 + t / 12;
    const int j = t % 12;
    const int hh = j & 3;
    const float* wr = W + i * 256 + hh * 64;
    float acc = 0.f;
    if (j < 8) {
      const float* v = (j < 4 ? a_src : a_dst) + hh * 64;
#pragma unroll
      for (int c = 0; c < 64; c += 4) {
        float4 wv = *(const float4*)(wr + c);
        float4 vv = *(const float4*)(v + c);
        acc += wv.x * vv.x + wv.y * vv.y + wv.z * vv.z + wv.w * vv.w;
      }
    } else {
#pragma unroll
      for (int c = 0; c < 64; ++c) acc += wr[c] * ql[hh * 64 + c];
    }
    Mg[i * 12 + j] = acc;
  }
}

// ---------------- prep_node v2: LDS-staged, no shuffles ----------------
// 64 nodes/block; x staged [64][132], Mg transposed [12][132]; 4 threads/node
// computing 3 dot-128 each via float4 LDS reads.
__global__ __launch_bounds__(256) void prep_node_kernel(const float* __restrict__ x,
                                                        const float* __restrict__ Mg,
                                                        float* __restrict__ al_s,
                                                        float* __restrict__ al_d,
                                                        float* __restrict__ hq) {
  __shared__ float xs[64][132];
  __shared__ float MsT[12][132];
  const int t = threadIdx.x;
  const int n0 = blockIdx.x * 64;
  for (int r = t; r < 1536; r += 256) MsT[r % 12][r / 12] = Mg[r];
#pragma unroll
  for (int u = 0; u < 8; ++u) {
    int idx = u * 256 + t;                          // 0..2047 = node*32 + c4
    int node = idx >> 5, c4 = idx & 31;
    *(float4*)(&xs[node][c4 * 4]) =
        *(const float4*)(x + (size_t)(n0 + node) * 128 + c4 * 4);
  }
  __syncthreads();
  const int node = t >> 2, q = t & 3;
  const int j0 = q * 3;
  float a0 = 0.f, a1 = 0.f, a2 = 0.f;
#pragma unroll
  for (int c4 = 0; c4 < 32; ++c4) {
    float4 xv = *(const float4*)(&xs[node][c4 * 4]);
    float4 m0 = *(const float4*)(&MsT[j0 + 0][c4 * 4]);
    float4 m1 = *(const float4*)(&MsT[j0 + 1][c4 * 4]);
    float4 m2 = *(const float4*)(&MsT[j0 + 2][c4 * 4]);
    a0 += xv.x * m0.x + xv.y * m0.y + xv.z * m0.z + xv.w * m0.w;
    a1 += xv.x * m1.x + xv.y * m1.y + xv.z * m1.z + xv.w * m1.w;
    a2 += xv.x * m2.x + xv.y * m2.y + xv.z * m2.z + xv.w * m2.w;
  }
  const int n = n0 + node;
  float vals[3] = {a0, a1, a2};
#pragma unroll
  for (int k = 0; k < 3; ++k) {
    int j = j0 + k;
    float* base = (j < 4) ? al_s : ((j < 8) ? al_d : hq);
    int jj = (j < 4) ? j : ((j < 8) ? j - 4 : j - 8);
    base[n * 4 + jj] = vals[k];
  }
}

// ---------------- CSR build: edge-parallel ----------------
__global__ void count_kernel(const int* __restrict__ ei, int* __restrict__ cnt) {
  int e = blockIdx.x * 256 + threadIdx.x;
  if (e >= EE) return;
  atomicAdd(&cnt[ei[EE + e]], 1);
}

__global__ __launch_bounds__(1024) void scan_g_kernel(const int* __restrict__ cnt,
                                                      int* __restrict__ row_ptr,
                                                      int* __restrict__ cnt2) {
  __shared__ int sums[NPG];
  const int b = blockIdx.x, t = threadIdx.x;
  const int c = cnt[b * NPG + t] + 1;               // + self-loop
  sums[t] = c;
  __syncthreads();
  for (int off = 1; off < NPG; off <<= 1) {
    int v = (t >= off) ? sums[t - off] : 0;
    __syncthreads();
    sums[t] += v;
    __syncthreads();
  }
  const int pos = b * RPG + sums[t] - c;
  row_ptr[b * NPG + t] = pos;
  cnt2[b * NPG + t] = pos;
  if (b == 0 && t == 0) row_ptr[NN] = ETOT;
}

__global__ void scatter_w_kernel(const int* __restrict__ ei,
                                 int* __restrict__ cnt2,
                                 const float* __restrict__ al_s,
                                 const float* __restrict__ al_d,
                                 int* __restrict__ col, float* __restrict__ w4) {
  int e = blockIdx.x * 256 + threadIdx.x;
  if (e >= ETOT) return;
  int s, d;
  if (e < EE) { s = ei[e]; d = ei[EE + e]; } else { s = e - EE; d = s; }
  int pos = atomicAdd(&cnt2[d], 1);
  col[pos] = s;
  const float4 as = *(const float4*)(al_s + s * NH);
  const float4 ad = *(const float4*)(al_d + d * NH);
  float e0 = as.x + ad.x; e0 = (e0 > 0.f) ? e0 : SLOPE * e0; float w0 = __expf(e0);
  float e1 = as.y + ad.y; e1 = (e1 > 0.f) ? e1 : SLOPE * e1; float w1 = __expf(e1);
  float e2 = as.z + ad.z; e2 = (e2 > 0.f) ? e2 : SLOPE * e2; float w2 = __expf(e2);
  float e3 = as.w + ad.w; e3 = (e3 > 0.f) ? e3 : SLOPE * e3; float w3 = __expf(e3);
  *(float4*)(w4 + (size_t)pos * 4) = make_float4(w0, w1, w2, w3);
}

// ---------------- GEMM1 (MFMA bf16, no LDS) ----------------
__global__ __launch_bounds__(256) void gemm1_kernel(const float* __restrict__ x,
                                                    const unsigned short* __restrict__ Wt,
                                                    unsigned short* __restrict__ hbf) {
  const int lane = threadIdx.x & 63;
  const int wv = threadIdx.x >> 6;
  const int q = lane >> 4, nh = lane & 15;
  const int lid = blockIdx.x;                       // 512 blocks = 8 xcd x 64
  const int node = ((lid & 7) * 64 + (lid >> 3)) * 64 + wv * 16 + nh;
  f32x4 acc[16];
#pragma unroll
  for (int mt = 0; mt < 16; ++mt) acc[mt] = (f32x4){0.f, 0.f, 0.f, 0.f};
  const float* xr = x + (size_t)node * 128;
#pragma unroll
  for (int kc = 0; kc < 4; ++kc) {
    const float* xp = xr + kc * 32 + q * 8;
    float4 v0 = *(const float4*)(xp);
    float4 v1 = *(const float4*)(xp + 4);
    short8 b;
    b[0] = (short)f2bf(v0.x); b[1] = (short)f2bf(v0.y);
    b[2] = (short)f2bf(v0.z); b[3] = (short)f2bf(v0.w);
    b[4] = (short)f2bf(v1.x); b[5] = (short)f2bf(v1.y);
    b[6] = (short)f2bf(v1.z); b[7] = (short)f2bf(v1.w);
#pragma unroll
    for (int mt = 0; mt < 16; ++mt) {
      short8 a = *(const short8*)(Wt + (size_t)(mt * 16 + nh) * 128 + kc * 32 + q * 8);
      acc[mt] = __builtin_amdgcn_mfma_f32_16x16x32_bf16(a, b, acc[mt], 0, 0, 0);
    }
  }
  unsigned short* hr = hbf + (size_t)node * 256;
#pragma unroll
  for (int mt = 0; mt < 16; ++mt) {
    ushort4 o;
    o.x = f2bf(acc[mt][0]); o.y = f2bf(acc[mt][1]);
    o.z = f2bf(acc[mt][2]); o.w = f2bf(acc[mt][3]);
    *(ushort4*)(hr + mt * 16 + q * 4) = o;
  }
}

// ---------------- aggregation v3: 16-edge groups, double-buffered registers ----
// Zero-padded slots (w=0) make extra iterations exact no-ops; accumulation
// order over real edges unchanged -> outg value-identical.
__global__ __launch_bounds__(256) void agg_kernel(const unsigned short* __restrict__ h,
                                                  const float* __restrict__ w4,
                                                  const float* __restrict__ hq,
                                                  const int* __restrict__ row_ptr,
                                                  const int* __restrict__ col,
                                                  const float* __restrict__ b_gat,
                                                  const float* __restrict__ cbuf,
                                                  unsigned short* __restrict__ outg,
                                                  float* __restrict__ score) {
  __shared__ float wsh[4][256];
  __shared__ float qsh[4][256];
  __shared__ int   osh[4][64];
  const int lane = threadIdx.x & 63;
  const int wv = threadIdx.x >> 6;
  const int hqi = lane >> 4;
  const int xcd = blockIdx.x & 7;
  const int jb = blockIdx.x >> 3;
  const int n = (xcd * 1024 + jb) * 4 + wv;
  const int beg = row_ptr[n], end = row_ptr[n + 1];
  const char* hbase = (const char*)h + (size_t)lane * 8;
  float ax = 0.f, ay = 0.f, az = 0.f, aw = 0.f, den = 0.f, sq = 0.f;

  uint2 bufA[16], bufB[16];
  auto loadg = [&](uint2 (&buf)[16], int slot0) {
#pragma unroll
    for (int k = 0; k < 16; ++k)
      buf[k] = *(const uint2*)(hbase + osh[wv][slot0 + k]);
  };
  auto computeg = [&](uint2 (&buf)[16], int slot0) {
#pragma unroll
    for (int k = 0; k < 16; ++k) {
      const float w = wsh[wv][(slot0 + k) * 4 + hqi];
      const float qv = qsh[wv][(slot0 + k) * 4 + hqi];
      uint2 cur = buf[k];
      den += w; sq += w * qv;
      ax += w * __uint_as_float(cur.x << 16);
      ay += w * __uint_as_float(cur.x & 0xffff0000u);
      az += w * __uint_as_float(cur.y << 16);
      aw += w * __uint_as_float(cur.y & 0xffff0000u);
    }
  };

  for (int base = beg; base < end; base += 64) {
    const int rem = end - base;
    const int cnt = rem < 64 ? rem : 64;
    // stage (zero-fill beyond cnt: w=0 -> exact no-op slots)
    int c = 0;
    float4 wv4 = make_float4(0.f, 0.f, 0.f, 0.f);
    float4 qv4 = make_float4(0.f, 0.f, 0.f, 0.f);
    if (lane < cnt) {
      c = col[base + lane];
      wv4 = *(const float4*)(w4 + (size_t)(base + lane) * 4);
      qv4 = *(const float4*)(hq + (size_t)c * 4);
    }
    osh[wv][lane] = c << 9;                          // byte offset (256 ch x 2B)
    *(float4*)(&wsh[wv][lane * 4]) = wv4;
    *(float4*)(&qsh[wv][lane * 4]) = qv4;
    // wave-coherent LDS region (per-wave): no barrier needed
    const int groups = (cnt + 15) >> 4;
    loadg(bufA, 0);
    for (int g = 0; g < groups; g += 2) {
      if (g + 1 < groups) loadg(bufB, (g + 1) * 16);
      computeg(bufA, g * 16);
      if (g + 1 < groups) {
        if (g + 2 < groups) loadg(bufA, (g + 2) * 16);
        computeg(bufB, (g + 1) * 16);
      }
    }
  }
  const float4 bg = *(const float4*)(b_gat + lane * 4);
  ushort4 ov;
  ov.x = f2bf(ax / den + bg.x); ov.y = f2bf(ay / den + bg.y);
  ov.z = f2bf(az / den + bg.z); ov.w = f2bf(aw / den + bg.w);
  *(ushort4*)(outg + (size_t)n * 256 + lane * 4) = ov;
  float sd = sq / den;                              // per-head (uniform within head)
  float s0v = __shfl(sd, 0), s1v = __shfl(sd, 16);
  float s2v = __shfl(sd, 32), s3v = __shfl(sd, 48);
  if (lane == 0)
    score[n] = tanhf((s0v + s1v + s2v + s3v + cbuf[0]) * cbuf[1]);
}

// ---------------- GEMM2 (MFMA bf16, no LDS) ----------------
__global__ __launch_bounds__(256) void gemm2_kernel(const unsigned short* __restrict__ outg,
                                                    const unsigned short* __restrict__ Wlt,
                                                    const float* __restrict__ bl,
                                                    float* __restrict__ xl) {
  const int lane = threadIdx.x & 63;
  const int wv = threadIdx.x >> 6;
  const int q = lane >> 4, nh = lane & 15;
  const int lid = blockIdx.x;
  const int node = ((lid & 7) * 64 + (lid >> 3)) * 64 + wv * 16 + nh;
  f32x4 acc[4];
#pragma unroll
  for (int mt = 0; mt < 4; ++mt) acc[mt] = (f32x4){0.f, 0.f, 0.f, 0.f};
  const unsigned short* ar = outg + (size_t)node * 256;
#pragma unroll
  for (int kc = 0; kc < 8; ++kc) {
    short8 b = *(const short8*)(ar + kc * 32 + q * 8);
#pragma unroll
    for (int mt = 0; mt < 4; ++mt) {
      short8 a = *(const short8*)(Wlt + (size_t)(mt * 16 + nh) * 256 + kc * 32 + q * 8);
      acc[mt] = __builtin_amdgcn_mfma_f32_16x16x32_bf16(a, b, acc[mt], 0, 0, 0);
    }
  }
#pragma unroll
  for (int mt = 0; mt < 4; ++mt) {
    const int c4 = mt * 16 + q * 4;
    float4 bl4 = *(const float4*)(bl + c4);
    float4 o = make_float4(acc[mt][0] + bl4.x, acc[mt][1] + bl4.y,
                           acc[mt][2] + bl4.z, acc[mt][3] + bl4.w);
    *(float4*)(xl + (size_t)node * 64 + c4) = o;
  }
}

// ---------------- fused top-k + xp + nmap + pool ----------------
__device__ inline unsigned long long shflx64(unsigned long long v, int m) {
  int lo = __shfl_xor((int)(unsigned)v, m, 64);
  int hi = __shfl_xor((int)(unsigned)(v >> 32), m, 64);
  return ((unsigned long long)(unsigned)hi << 32) | (unsigned)lo;
}

__global__ __launch_bounds__(1024) void topk_fused_kernel(const float* __restrict__ xl,
                                                          const float* __restrict__ score,
                                                          float* __restrict__ out_xp,
                                                          int* __restrict__ nmap,
                                                          float* __restrict__ out_batch,
                                                          float* __restrict__ out_x1) {
  __shared__ float scv[NPG];
  __shared__ unsigned long long keys[NPG];
  __shared__ int   pidx[KK];
  __shared__ float tvs[KK];
  __shared__ float ps[16][64];
  __shared__ float pm[16][64];
  const int b = blockIdx.x, t = threadIdx.x;
  float sc = score[b * NPG + t];
  scv[t] = sc;
  nmap[b * NPG + t] = -1;
  unsigned long long v;
  {
    unsigned u = __float_as_uint(sc);
    u = (u & 0x80000000u) ? ~u : (u | 0x80000000u);
    u = ~u;
    v = ((unsigned long long)u << 32) | (unsigned)t;
  }
  __syncthreads();
  for (int k = 2; k <= NPG; k <<= 1) {
    for (int j = k >> 1; j > 0; j >>= 1) {
      unsigned long long pv;
      if (j >= 64) {
        keys[t] = v;
        __syncthreads();
        pv = keys[t ^ j];
        __syncthreads();
      } else {
        pv = shflx64(v, j);
      }
      bool up = ((t & k) == 0);
      bool small_side = ((t & j) == 0);
      bool take_min = (small_side == up);
      v = take_min ? (v < pv ? v : pv) : (v > pv ? v : pv);
    }
  }
  if (t < KK) {
    int idx = (int)(v & 0xFFFFFFFFull);
    pidx[t] = idx;
    tvs[t] = scv[idx];
    nmap[b * NPG + idx] = b * KK + t;
    out_batch[b * KK + t] = (float)b;
  }
  __syncthreads();
  for (int u2 = t; u2 < KK * 16; u2 += 1024) {
    int row = u2 >> 4, qq = u2 & 15;
    int g = b * NPG + pidx[row];
    float4 vv = *(const float4*)(xl + (size_t)g * HID + qq * 4);
    float tv = tvs[row];
    vv.x *= tv; vv.y *= tv; vv.z *= tv; vv.w *= tv;
    *(float4*)(out_xp + (size_t)(b * KK + row) * HID + qq * 4) = vv;
  }
  __syncthreads();
  const int c = t & 63, rg = t >> 6;
  float s = 0.f, m = -INFINITY;
  for (int row = rg; row < KK; row += 16) {
    float vv = out_xp[(size_t)(b * KK + row) * HID + c];
    s += vv; m = fmaxf(m, vv);
  }
  ps[rg][c] = s; pm[rg][c] = m;
  __syncthreads();
  if (t < 64) {
    float st = 0.f, mt = -INFINITY;
#pragma unroll
    for (int g2 = 0; g2 < 16; ++g2) { st += ps[g2][t]; mt = fmaxf(mt, pm[g2][t]); }
    out_x1[b * 128 + t] = st * (1.0f / KK);
    out_x1[b * 128 + 64 + t] = mt;
  }
}

// ---------------- edge remap / filter ----------------
__global__ void edge_out_kernel(const int* __restrict__ ei, const float* __restrict__ edge,
                                const int* __restrict__ nmap,
                                float* __restrict__ out_ei, float* __restrict__ out_edge) {
  int e = blockIdx.x * 256 + threadIdx.x;
  if (e >= EE) return;
  int s = ei[e], d = ei[EE + e];
  int ns = nmap[s], nd = nmap[d];
  bool valid = (ns >= 0) && (nd >= 0);
  out_ei[e] = (float)(valid ? ns : -1);
  out_ei[EE + e] = (float)(valid ? nd : -1);
  const float4* ef = (const float4*)(edge + (size_t)e * 8);
  float4 z = make_float4(0.f, 0.f, 0.f, 0.f);
  float4 v0 = valid ? ef[0] : z;
  float4 v1 = valid ? ef[1] : z;
  float4* eo = (float4*)(out_edge + (size_t)e * 8);
  eo[0] = v0; eo[1] = v1;
}

extern "C" void kernel_launch(void* const* d_in, const int* in_sizes, int n_in,
                              void* d_out, int out_size, void* d_ws, size_t ws_size,
                              hipStream_t stream) {
  const float* x      = (const float*)d_in[0];
  const int*   ei     = (const int*)d_in[1];
  const float* edge   = (const float*)d_in[2];
  const float* W      = (const float*)d_in[4];
  const float* a_src  = (const float*)d_in[5];
  const float* a_dst  = (const float*)d_in[6];
  const float* b_gat  = (const float*)d_in[7];
  const float* W_lin  = (const float*)d_in[8];
  const float* b_lin  = (const float*)d_in[9];
  const float* p_pool = (const float*)d_in[10];

  char* ws = (char*)d_ws;
  size_t off = 0;
  auto alloc = [&](size_t bytes) -> void* {
    void* p = ws + off;
    off += (bytes + 255) & ~(size_t)255;
    return p;
  };
  unsigned short* hbf  = (unsigned short*)alloc((size_t)NN * CC * 2);
  unsigned short* outg = (unsigned short*)alloc((size_t)NN * CC * 2);
  float* xl      = (float*)alloc((size_t)NN * HID * 4);
  float* al_s    = (float*)alloc((size_t)NN * NH * 4);
  float* al_d    = (float*)alloc((size_t)NN * NH * 4);
  float* hq      = (float*)alloc((size_t)NN * NH * 4);
  float* score   = (float*)alloc((size_t)NN * 4);
  int*   row_ptr = (int*)alloc((size_t)(NN + 1) * 4);
  int*   cnt     = (int*)alloc((size_t)NN * 4);
  int*   cnt2    = (int*)alloc((size_t)NN * 4);
  int*   col     = (int*)alloc((size_t)ETOT * 4);
  float* w4      = (float*)alloc((size_t)ETOT * NH * 4);
  int*   nmap    = (int*)alloc((size_t)NN * 4);
  unsigned short* Wt  = (unsigned short*)alloc((size_t)CC * INC * 2);
  unsigned short* Wlt = (unsigned short*)alloc((size_t)HID * CC * 2);
  float* Mg      = (float*)alloc((size_t)INC * 12 * 4);
  float* cbuf    = (float*)alloc(2 * 4);

  float* out_xp    = (float*)d_out;
  float* out_ei    = out_xp + (size_t)BB * KK * HID;
  float* out_edge  = out_ei + 2 * (size_t)EE;
  float* out_batch = out_edge + (size_t)EE * 8;
  float* out_x1    = out_batch + (size_t)BB * KK;

  hipMemsetAsync(cnt, 0, (size_t)NN * 4, stream);

  prep_kernel<<<209, 256, 0, stream>>>(W, a_src, a_dst, b_gat, W_lin, b_lin,
                                       p_pool, Mg, cbuf, Wt, Wlt);
  prep_node_kernel<<<NN / 64, 256, 0, stream>>>(x, Mg, al_s, al_d, hq);
  count_kernel<<<EE / 256, 256, 0, stream>>>(ei, cnt);
  gemm1_kernel<<<512, 256, 0, stream>>>(x, Wt, hbf);
  scan_g_kernel<<<BB, 1024, 0, stream>>>(cnt, row_ptr, cnt2);
  scatter_w_kernel<<<(ETOT + 255) / 256, 256, 0, stream>>>(ei, cnt2, al_s, al_d, col, w4);
  agg_kernel<<<NN / 4, 256, 0, stream>>>(hbf, w4, hq, row_ptr, col, b_gat, cbuf,
                                         outg, score);
  gemm2_kernel<<<512, 256, 0, stream>>>(outg, Wlt, b_lin, xl);
  topk_fused_kernel<<<BB, 1024, 0, stream>>>(xl, score, out_xp, nmap,
                                             out_batch, out_x1);
  edge_out_kernel<<<(EE + 255) / 256, 256, 0, stream>>>(ei, edge, nmap, out_ei, out_edge);
}

// Round 11
// 249.902 us; speedup vs baseline: 1.0820x; 1.0820x over previous
//
#include <hip/hip_runtime.h>
#include <math.h>

#define NN   32768
#define EE   524288
#define ETOT (EE + NN)
#define BB   32
#define NPG  1024
#define RPG  17408          // CSR entries per graph = 16384 + 1024 self-loops
#define KK   512
#define INC  128
#define HID  64
#define NH   4
#define CC   256
#define SLOPE 0.2f

typedef __attribute__((ext_vector_type(8))) short short8;   // 8 bf16 = 4 VGPRs
typedef __attribute__((ext_vector_type(4))) float f32x4;

static __device__ inline unsigned short f2bf(float f) {      // fp32 -> bf16 RNE
  unsigned u = __float_as_uint(f);
  unsigned r = (u + 0x7FFFu + ((u >> 16) & 1u)) >> 16;
  return (unsigned short)r;
}

// ---------------- prep: consts + Mg + bf16 transposes + cnt zeroing ----------------
// block 0: cq/rnorm; 1..16: Mg; 17..208: Wt/Wlt transposes; 209..336: cnt = 0.
__global__ __launch_bounds__(256) void prep_kernel(const float* __restrict__ W,
                                                   const float* __restrict__ a_src,
                                                   const float* __restrict__ a_dst,
                                                   const float* __restrict__ b_gat,
                                                   const float* __restrict__ W_lin,
                                                   const float* __restrict__ b_lin,
                                                   const float* __restrict__ p,
                                                   float* __restrict__ Mg,
                                                   float* __restrict__ cbuf,
                                                   unsigned short* __restrict__ Wt,
                                                   unsigned short* __restrict__ Wlt,
                                                   int* __restrict__ cnt) {
  const int b = blockIdx.x, t = threadIdx.x;
  if (b >= 209) {                                   // cnt zeroing (replaces memset)
    cnt[(b - 209) * 256 + t] = 0;
    return;
  }
  if (b >= 17) {                                    // transposes
    int idx = (b - 17) * 256 + t;
    if (idx < 32768) {                              // Wt[c][k] = W[k][c]
      int c = idx >> 7, k = idx & 127;
      Wt[idx] = f2bf(W[k * 256 + c]);
    } else {                                        // Wlt[c][k] = W_lin[k][c]
      int i2 = idx - 32768;
      int c = i2 >> 8, k = i2 & 255;
      Wlt[i2] = f2bf(W_lin[k * 64 + c]);
    }
    return;
  }
  __shared__ float pl[64];
  __shared__ float ql[256];
  __shared__ float red[256];
  __shared__ float red2[256];
  if (t < 64) pl[t] = p[t];
  __syncthreads();
  {                                                 // q[t] = dot(W_lin[t], p)
    float acc = 0.f;
    const float* wr = W_lin + t * 64;
#pragma unroll
    for (int c = 0; c < 64; c += 4) {
      float4 wv = *(const float4*)(wr + c);
      acc += wv.x * pl[c] + wv.y * pl[c + 1] + wv.z * pl[c + 2] + wv.w * pl[c + 3];
    }
    ql[t] = acc;
  }
  __syncthreads();
  if (b == 0) {                                     // cq + rnorm via LDS trees
    float r = ql[t] * b_gat[t];
    if (t < 64) r += b_lin[t] * pl[t];
    red[t] = r;
    red2[t] = (t < 64) ? pl[t] * pl[t] : 0.f;
    __syncthreads();
    for (int s2 = 128; s2 > 0; s2 >>= 1) {
      if (t < s2) { red[t] += red[t + s2]; red2[t] += red2[t + s2]; }
      __syncthreads();
    }
    if (t == 0) { cbuf[0] = red[0]; cbuf[1] = 1.0f / sqrtf(red2[0]); }
    return;
  }
  if (t < 96) {                                     // blocks 1..16: 8 rows x 12 cols
    const int i = (b - 1) * 8 + t / 12;
    const int j = t % 12;
    const int hh = j & 3;
    const float* wr = W + i * 256 + hh * 64;
    float acc = 0.f;
    if (j < 8) {
      const float* v = (j < 4 ? a_src : a_dst) + hh * 64;
#pragma unroll
      for (int c = 0; c < 64; c += 4) {
        float4 wv = *(const float4*)(wr + c);
        float4 vv = *(const float4*)(v + c);
        acc += wv.x * vv.x + wv.y * vv.y + wv.z * vv.z + wv.w * vv.w;
      }
    } else {
#pragma unroll
      for (int c = 0; c < 64; ++c) acc += wr[c] * ql[hh * 64 + c];
    }
    Mg[i * 12 + j] = acc;
  }
}

// ---------------- prep_node v2 (R10-proven): LDS-staged, no shuffles ----------------
__global__ __launch_bounds__(256) void prep_node_kernel(const float* __restrict__ x,
                                                        const float* __restrict__ Mg,
                                                        float* __restrict__ al_s,
                                                        float* __restrict__ al_d,
                                                        float* __restrict__ hq) {
  __shared__ float xs[64][132];
  __shared__ float MsT[12][132];
  const int t = threadIdx.x;
  const int n0 = blockIdx.x * 64;
  for (int r = t; r < 1536; r += 256) MsT[r % 12][r / 12] = Mg[r];
#pragma unroll
  for (int u = 0; u < 8; ++u) {
    int idx = u * 256 + t;                          // node*32 + c4
    int node = idx >> 5, c4 = idx & 31;
    *(float4*)(&xs[node][c4 * 4]) =
        *(const float4*)(x + (size_t)(n0 + node) * 128 + c4 * 4);
  }
  __syncthreads();
  const int node = t >> 2, q = t & 3;
  const int j0 = q * 3;
  float a0 = 0.f, a1 = 0.f, a2 = 0.f;
#pragma unroll
  for (int c4 = 0; c4 < 32; ++c4) {
    float4 xv = *(const float4*)(&xs[node][c4 * 4]);
    float4 m0 = *(const float4*)(&MsT[j0 + 0][c4 * 4]);
    float4 m1 = *(const float4*)(&MsT[j0 + 1][c4 * 4]);
    float4 m2 = *(const float4*)(&MsT[j0 + 2][c4 * 4]);
    a0 += xv.x * m0.x + xv.y * m0.y + xv.z * m0.z + xv.w * m0.w;
    a1 += xv.x * m1.x + xv.y * m1.y + xv.z * m1.z + xv.w * m1.w;
    a2 += xv.x * m2.x + xv.y * m2.y + xv.z * m2.z + xv.w * m2.w;
  }
  const int n = n0 + node;
  float vals[3] = {a0, a1, a2};
#pragma unroll
  for (int k = 0; k < 3; ++k) {
    int j = j0 + k;
    float* base = (j < 4) ? al_s : ((j < 8) ? al_d : hq);
    int jj = (j < 4) ? j : ((j < 8) ? j - 4 : j - 8);
    base[n * 4 + jj] = vals[k];
  }
}

// ---------------- GEMM1 (MFMA bf16, no LDS) + fused edge count ----------------
__global__ __launch_bounds__(256) void gemm1_kernel(const float* __restrict__ x,
                                                    const unsigned short* __restrict__ Wt,
                                                    const int* __restrict__ ei,
                                                    int* __restrict__ cnt,
                                                    unsigned short* __restrict__ hbf) {
  const int lane = threadIdx.x & 63;
  const int wv = threadIdx.x >> 6;
  const int q = lane >> 4, nh = lane & 15;
  const int lid = blockIdx.x;                       // 512 blocks = 8 xcd x 64
  const int node = ((lid & 7) * 64 + (lid >> 3)) * 64 + wv * 16 + nh;
  // fused edge count (cnt zeroed by prep): 512x256x4 = EE edges
  const int e4 = (lid * 256 + threadIdx.x) * 4;
  const int4 d4 = *(const int4*)(ei + EE + e4);
  f32x4 acc[16];
#pragma unroll
  for (int mt = 0; mt < 16; ++mt) acc[mt] = (f32x4){0.f, 0.f, 0.f, 0.f};
  const float* xr = x + (size_t)node * 128;
#pragma unroll
  for (int kc = 0; kc < 4; ++kc) {
    const float* xp = xr + kc * 32 + q * 8;
    float4 v0 = *(const float4*)(xp);
    float4 v1 = *(const float4*)(xp + 4);
    short8 b;
    b[0] = (short)f2bf(v0.x); b[1] = (short)f2bf(v0.y);
    b[2] = (short)f2bf(v0.z); b[3] = (short)f2bf(v0.w);
    b[4] = (short)f2bf(v1.x); b[5] = (short)f2bf(v1.y);
    b[6] = (short)f2bf(v1.z); b[7] = (short)f2bf(v1.w);
#pragma unroll
    for (int mt = 0; mt < 16; ++mt) {
      short8 a = *(const short8*)(Wt + (size_t)(mt * 16 + nh) * 128 + kc * 32 + q * 8);
      acc[mt] = __builtin_amdgcn_mfma_f32_16x16x32_bf16(a, b, acc[mt], 0, 0, 0);
    }
  }
  atomicAdd(&cnt[d4.x], 1);
  atomicAdd(&cnt[d4.y], 1);
  atomicAdd(&cnt[d4.z], 1);
  atomicAdd(&cnt[d4.w], 1);
  unsigned short* hr = hbf + (size_t)node * 256;
#pragma unroll
  for (int mt = 0; mt < 16; ++mt) {
    ushort4 o;
    o.x = f2bf(acc[mt][0]); o.y = f2bf(acc[mt][1]);
    o.z = f2bf(acc[mt][2]); o.w = f2bf(acc[mt][3]);
    *(ushort4*)(hr + mt * 16 + q * 4) = o;
  }
}

// ---------------- CSR scan (per-graph LDS) ----------------
__global__ __launch_bounds__(1024) void scan_g_kernel(const int* __restrict__ cnt,
                                                      int* __restrict__ row_ptr,
                                                      int* __restrict__ cnt2) {
  __shared__ int sums[NPG];
  const int b = blockIdx.x, t = threadIdx.x;
  const int c = cnt[b * NPG + t] + 1;               // + self-loop
  sums[t] = c;
  __syncthreads();
  for (int off = 1; off < NPG; off <<= 1) {
    int v = (t >= off) ? sums[t - off] : 0;
    __syncthreads();
    sums[t] += v;
    __syncthreads();
  }
  const int pos = b * RPG + sums[t] - c;
  row_ptr[b * NPG + t] = pos;
  cnt2[b * NPG + t] = pos;
  if (b == 0 && t == 0) row_ptr[NN] = ETOT;
}

// ---------------- scatter: col only (weights moved into agg staging) ----------------
__global__ void scatter_kernel(const int* __restrict__ ei,
                               int* __restrict__ cnt2,
                               int* __restrict__ col) {
  int e = blockIdx.x * 256 + threadIdx.x;
  if (e >= ETOT) return;
  int s, d;
  if (e < EE) { s = ei[e]; d = ei[EE + e]; } else { s = e - EE; d = s; }
  int pos = atomicAdd(&cnt2[d], 1);
  col[pos] = s;
}

// ---------------- aggregation (R9 structure): 4-deep clamped prefetch; ----------------
// exp computed in staging (1 edge/lane) from al_s[c]+al_d[n] — same expression
// and accumulation order as scatter_w-based versions -> outg bit-identical.
__global__ __launch_bounds__(256) void agg_kernel(const unsigned short* __restrict__ h,
                                                  const float* __restrict__ al_s,
                                                  const float* __restrict__ al_d,
                                                  const float* __restrict__ hq,
                                                  const int* __restrict__ row_ptr,
                                                  const int* __restrict__ col,
                                                  const float* __restrict__ b_gat,
                                                  const float* __restrict__ cbuf,
                                                  unsigned short* __restrict__ outg,
                                                  float* __restrict__ score) {
  __shared__ float wsh[4][256];
  __shared__ float qsh[4][256];
  __shared__ int   osh[4][64];
  const int lane = threadIdx.x & 63;
  const int wv = threadIdx.x >> 6;
  const int hqi = lane >> 4;                        // head of this lane
  const int xcd = blockIdx.x & 7;
  const int jb = blockIdx.x >> 3;
  const int n = (xcd * 1024 + jb) * 4 + wv;
  const int beg = row_ptr[n], end = row_ptr[n + 1];
  const float4 ad4 = *(const float4*)(al_d + (size_t)n * 4);   // wave-uniform
  const char* hbase = (const char*)h + (size_t)lane * 8;
  float ax = 0.f, ay = 0.f, az = 0.f, aw = 0.f, den = 0.f, sq = 0.f;
  for (int base = beg; base < end; base += 64) {
    const int rem = end - base;
    const int cnt = rem < 64 ? rem : 64;
    if (lane < cnt) {
      const int c = col[base + lane];
      osh[wv][lane] = c << 9;                        // byte offset (256 ch x 2B)
      const float4 as = *(const float4*)(al_s + (size_t)c * 4);
      float e0 = as.x + ad4.x; e0 = (e0 > 0.f) ? e0 : SLOPE * e0;
      float e1 = as.y + ad4.y; e1 = (e1 > 0.f) ? e1 : SLOPE * e1;
      float e2 = as.z + ad4.z; e2 = (e2 > 0.f) ? e2 : SLOPE * e2;
      float e3 = as.w + ad4.w; e3 = (e3 > 0.f) ? e3 : SLOPE * e3;
      *(float4*)(&wsh[wv][lane * 4]) =
          make_float4(__expf(e0), __expf(e1), __expf(e2), __expf(e3));
      *(float4*)(&qsh[wv][lane * 4]) = *(const float4*)(hq + (size_t)c * 4);
    }
    // wave-coherent LDS region (per-wave, no barrier needed)
    const int cm1 = cnt - 1;
    uint2 v0 = *(const uint2*)(hbase + osh[wv][0]);
    uint2 v1 = *(const uint2*)(hbase + osh[wv][1 > cm1 ? cm1 : 1]);
    uint2 v2 = *(const uint2*)(hbase + osh[wv][2 > cm1 ? cm1 : 2]);
    uint2 v3 = *(const uint2*)(hbase + osh[wv][3 > cm1 ? cm1 : 3]);
    for (int i = 0; i < cnt; ++i) {
      const float w = wsh[wv][i * 4 + hqi];
      const float hqv = qsh[wv][i * 4 + hqi];
      uint2 cur = v0; v0 = v1; v1 = v2; v2 = v3;
      int ni = i + 4; ni = ni > cm1 ? cm1 : ni;
      v3 = *(const uint2*)(hbase + osh[wv][ni]);
      den += w; sq += w * hqv;
      ax += w * __uint_as_float(cur.x << 16);
      ay += w * __uint_as_float(cur.x & 0xffff0000u);
      az += w * __uint_as_float(cur.y << 16);
      aw += w * __uint_as_float(cur.y & 0xffff0000u);
    }
  }
  const float4 bg = *(const float4*)(b_gat + lane * 4);
  ushort4 ov;
  ov.x = f2bf(ax / den + bg.x); ov.y = f2bf(ay / den + bg.y);
  ov.z = f2bf(az / den + bg.z); ov.w = f2bf(aw / den + bg.w);
  *(ushort4*)(outg + (size_t)n * 256 + lane * 4) = ov;
  float sd = sq / den;                              // per-head (uniform within head)
  float s0v = __shfl(sd, 0), s1v = __shfl(sd, 16);
  float s2v = __shfl(sd, 32), s3v = __shfl(sd, 48);
  if (lane == 0)
    score[n] = tanhf((s0v + s1v + s2v + s3v + cbuf[0]) * cbuf[1]);
}

// ---------------- GEMM2 (MFMA bf16, no LDS) ----------------
__global__ __launch_bounds__(256) void gemm2_kernel(const unsigned short* __restrict__ outg,
                                                    const unsigned short* __restrict__ Wlt,
                                                    const float* __restrict__ bl,
                                                    float* __restrict__ xl) {
  const int lane = threadIdx.x & 63;
  const int wv = threadIdx.x >> 6;
  const int q = lane >> 4, nh = lane & 15;
  const int lid = blockIdx.x;
  const int node = ((lid & 7) * 64 + (lid >> 3)) * 64 + wv * 16 + nh;
  f32x4 acc[4];
#pragma unroll
  for (int mt = 0; mt < 4; ++mt) acc[mt] = (f32x4){0.f, 0.f, 0.f, 0.f};
  const unsigned short* ar = outg + (size_t)node * 256;
#pragma unroll
  for (int kc = 0; kc < 8; ++kc) {
    short8 b = *(const short8*)(ar + kc * 32 + q * 8);
#pragma unroll
    for (int mt = 0; mt < 4; ++mt) {
      short8 a = *(const short8*)(Wlt + (size_t)(mt * 16 + nh) * 256 + kc * 32 + q * 8);
      acc[mt] = __builtin_amdgcn_mfma_f32_16x16x32_bf16(a, b, acc[mt], 0, 0, 0);
    }
  }
#pragma unroll
  for (int mt = 0; mt < 4; ++mt) {
    const int c4 = mt * 16 + q * 4;
    float4 bl4 = *(const float4*)(bl + c4);
    float4 o = make_float4(acc[mt][0] + bl4.x, acc[mt][1] + bl4.y,
                           acc[mt][2] + bl4.z, acc[mt][3] + bl4.w);
    *(float4*)(xl + (size_t)node * 64 + c4) = o;
  }
}

// ---------------- fused top-k + xp + nmap + pool ----------------
__device__ inline unsigned long long shflx64(unsigned long long v, int m) {
  int lo = __shfl_xor((int)(unsigned)v, m, 64);
  int hi = __shfl_xor((int)(unsigned)(v >> 32), m, 64);
  return ((unsigned long long)(unsigned)hi << 32) | (unsigned)lo;
}

__global__ __launch_bounds__(1024) void topk_fused_kernel(const float* __restrict__ xl,
                                                          const float* __restrict__ score,
                                                          float* __restrict__ out_xp,
                                                          int* __restrict__ nmap,
                                                          float* __restrict__ out_batch,
                                                          float* __restrict__ out_x1) {
  __shared__ float scv[NPG];
  __shared__ unsigned long long keys[NPG];
  __shared__ int   pidx[KK];
  __shared__ float tvs[KK];
  __shared__ float ps[16][64];
  __shared__ float pm[16][64];
  const int b = blockIdx.x, t = threadIdx.x;
  float sc = score[b * NPG + t];
  scv[t] = sc;
  nmap[b * NPG + t] = -1;
  unsigned long long v;
  {
    unsigned u = __float_as_uint(sc);
    u = (u & 0x80000000u) ? ~u : (u | 0x80000000u);
    u = ~u;
    v = ((unsigned long long)u << 32) | (unsigned)t;
  }
  __syncthreads();
  for (int k = 2; k <= NPG; k <<= 1) {
    for (int j = k >> 1; j > 0; j >>= 1) {
      unsigned long long pv;
      if (j >= 64) {
        keys[t] = v;
        __syncthreads();
        pv = keys[t ^ j];
        __syncthreads();
      } else {
        pv = shflx64(v, j);
      }
      bool up = ((t & k) == 0);
      bool small_side = ((t & j) == 0);
      bool take_min = (small_side == up);
      v = take_min ? (v < pv ? v : pv) : (v > pv ? v : pv);
    }
  }
  if (t < KK) {
    int idx = (int)(v & 0xFFFFFFFFull);
    pidx[t] = idx;
    tvs[t] = scv[idx];
    nmap[b * NPG + idx] = b * KK + t;
    out_batch[b * KK + t] = (float)b;
  }
  __syncthreads();
  for (int u2 = t; u2 < KK * 16; u2 += 1024) {
    int row = u2 >> 4, qq = u2 & 15;
    int g = b * NPG + pidx[row];
    float4 vv = *(const float4*)(xl + (size_t)g * HID + qq * 4);
    float tv = tvs[row];
    vv.x *= tv; vv.y *= tv; vv.z *= tv; vv.w *= tv;
    *(float4*)(out_xp + (size_t)(b * KK + row) * HID + qq * 4) = vv;
  }
  __syncthreads();
  const int c = t & 63, rg = t >> 6;
  float s = 0.f, m = -INFINITY;
  for (int row = rg; row < KK; row += 16) {
    float vv = out_xp[(size_t)(b * KK + row) * HID + c];
    s += vv; m = fmaxf(m, vv);
  }
  ps[rg][c] = s; pm[rg][c] = m;
  __syncthreads();
  if (t < 64) {
    float st = 0.f, mt = -INFINITY;
#pragma unroll
    for (int g2 = 0; g2 < 16; ++g2) { st += ps[g2][t]; mt = fmaxf(mt, pm[g2][t]); }
    out_x1[b * 128 + t] = st * (1.0f / KK);
    out_x1[b * 128 + 64 + t] = mt;
  }
}

// ---------------- edge remap / filter ----------------
__global__ void edge_out_kernel(const int* __restrict__ ei, const float* __restrict__ edge,
                                const int* __restrict__ nmap,
                                float* __restrict__ out_ei, float* __restrict__ out_edge) {
  int e = blockIdx.x * 256 + threadIdx.x;
  if (e >= EE) return;
  int s = ei[e], d = ei[EE + e];
  int ns = nmap[s], nd = nmap[d];
  bool valid = (ns >= 0) && (nd >= 0);
  out_ei[e] = (float)(valid ? ns : -1);
  out_ei[EE + e] = (float)(valid ? nd : -1);
  const float4* ef = (const float4*)(edge + (size_t)e * 8);
  float4 z = make_float4(0.f, 0.f, 0.f, 0.f);
  float4 v0 = valid ? ef[0] : z;
  float4 v1 = valid ? ef[1] : z;
  float4* eo = (float4*)(out_edge + (size_t)e * 8);
  eo[0] = v0; eo[1] = v1;
}

extern "C" void kernel_launch(void* const* d_in, const int* in_sizes, int n_in,
                              void* d_out, int out_size, void* d_ws, size_t ws_size,
                              hipStream_t stream) {
  const float* x      = (const float*)d_in[0];
  const int*   ei     = (const int*)d_in[1];
  const float* edge   = (const float*)d_in[2];
  const float* W      = (const float*)d_in[4];
  const float* a_src  = (const float*)d_in[5];
  const float* a_dst  = (const float*)d_in[6];
  const float* b_gat  = (const float*)d_in[7];
  const float* W_lin  = (const float*)d_in[8];
  const float* b_lin  = (const float*)d_in[9];
  const float* p_pool = (const float*)d_in[10];

  char* ws = (char*)d_ws;
  size_t off = 0;
  auto alloc = [&](size_t bytes) -> void* {
    void* p = ws + off;
    off += (bytes + 255) & ~(size_t)255;
    return p;
  };
  unsigned short* hbf  = (unsigned short*)alloc((size_t)NN * CC * 2);
  unsigned short* outg = (unsigned short*)alloc((size_t)NN * CC * 2);
  float* xl      = (float*)alloc((size_t)NN * HID * 4);
  float* al_s    = (float*)alloc((size_t)NN * NH * 4);
  float* al_d    = (float*)alloc((size_t)NN * NH * 4);
  float* hq      = (float*)alloc((size_t)NN * NH * 4);
  float* score   = (float*)alloc((size_t)NN * 4);
  int*   row_ptr = (int*)alloc((size_t)(NN + 1) * 4);
  int*   cnt     = (int*)alloc((size_t)NN * 4);
  int*   cnt2    = (int*)alloc((size_t)NN * 4);
  int*   col     = (int*)alloc((size_t)ETOT * 4);
  int*   nmap    = (int*)alloc((size_t)NN * 4);
  unsigned short* Wt  = (unsigned short*)alloc((size_t)CC * INC * 2);
  unsigned short* Wlt = (unsigned short*)alloc((size_t)HID * CC * 2);
  float* Mg      = (float*)alloc((size_t)INC * 12 * 4);
  float* cbuf    = (float*)alloc(2 * 4);

  float* out_xp    = (float*)d_out;
  float* out_ei    = out_xp + (size_t)BB * KK * HID;
  float* out_edge  = out_ei + 2 * (size_t)EE;
  float* out_batch = out_edge + (size_t)EE * 8;
  float* out_x1    = out_batch + (size_t)BB * KK;

  prep_kernel<<<337, 256, 0, stream>>>(W, a_src, a_dst, b_gat, W_lin, b_lin,
                                       p_pool, Mg, cbuf, Wt, Wlt, cnt);
  prep_node_kernel<<<NN / 64, 256, 0, stream>>>(x, Mg, al_s, al_d, hq);
  gemm1_kernel<<<512, 256, 0, stream>>>(x, Wt, ei, cnt, hbf);
  scan_g_kernel<<<BB, 1024, 0, stream>>>(cnt, row_ptr, cnt2);
  scatter_kernel<<<(ETOT + 255) / 256, 256, 0, stream>>>(ei, cnt2, col);
  agg_kernel<<<NN / 4, 256, 0, stream>>>(hbf, al_s, al_d, hq, row_ptr, col,
                                         b_gat, cbuf, outg, score);
  gemm2_kernel<<<512, 256, 0, stream>>>(outg, Wlt, b_lin, xl);
  topk_fused_kernel<<<BB, 1024, 0, stream>>>(xl, score, out_xp, nmap,
                                             out_batch, out_x1);
  edge_out_kernel<<<(EE + 255) / 256, 256, 0, stream>>>(ei, edge, nmap, out_ei, out_edge);
}